// Round 14
// baseline (429.565 us; speedup 1.0000x reference)
//
#include <hip/hip_runtime.h>
#include <hip/hip_bf16.h>
#include <math.h>

using u16 = unsigned short;

static constexpr int SEQ = 1024;
static constexpr int DM  = 1024;
static constexpr int DHD = 64;

typedef __bf16 bfv8 __attribute__((ext_vector_type(8)));
typedef float  f32x4 __attribute__((ext_vector_type(4)));

__device__ __forceinline__ float u2f(u16 u) {
  return __uint_as_float(((unsigned int)u) << 16);
}
__device__ __forceinline__ u16 f2b(float x) {
  __hip_bfloat16 h = __float2bfloat16(x);
  return *reinterpret_cast<u16*>(&h);
}
__device__ __forceinline__ void gload16(const u16* g, u16* l) {
  __builtin_amdgcn_global_load_lds(
      (const __attribute__((address_space(1))) unsigned int*)g,
      (__attribute__((address_space(3))) unsigned int*)l, 16, 0, 0);
}

// ---------------------------------------------------------------------------
// 256x256-tile MFMA GEMM, 8 waves, BK=64, DBUF 128KB LDS.
// T1 col-major chunking: each XCD owns ~1 col-panel x all rows -> its B
// slice (0.5MB) stays L2-resident; A streams once from HBM, served to the
// other XCDs via the 256MB L3. ROT applied only to blocks with col0 < 1024.
// ---------------------------------------------------------------------------
template <int OT, bool HASBIAS, bool DOGELU, bool ROT>
__global__ __launch_bounds__(512) void mgemm256_k(
    const u16* __restrict__ A, const u16* __restrict__ Bt, void* __restrict__ C,
    int M, int K, int lda, int ldc, int coff, float alpha0, float alpha1, int acol,
    const float* __restrict__ bias, const float* __restrict__ tab) {
  __shared__ u16 As[2][256 * 64];
  __shared__ u16 Bs[2][256 * 64];
  const int tid = threadIdx.x;
  const int w = tid >> 6, lane = tid & 63;
  const int wm = w >> 2, wn = w & 3;
  const int lc = lane & 15;

  const int nwg = gridDim.x * gridDim.y;
  const int bid = blockIdx.y * gridDim.x + blockIdx.x;
  const int qq = nwg >> 3, r8 = nwg & 7;
  const int xcd = bid & 7, pos = bid >> 3;
  const int cbase = (xcd < r8) ? xcd * (qq + 1) : r8 * (qq + 1) + (xcd - r8) * qq;
  const int logical = cbase + pos;
  const int row0 = (logical % gridDim.y) << 8;   // rows fastest within a chunk
  const int col0 = (logical / gridDim.y) << 8;

  f32x4 acc[8][4] = {};

  auto STAGE = [&](int buf, int k0) {
#pragma unroll
    for (int i = 0; i < 4; ++i) {
      const int c = i * 512 + tid;
      const int r = c >> 3;
      const int cbs = ((c & 7) ^ (r & 7)) << 3;
      gload16(A + (size_t)(row0 + r) * lda + k0 + cbs, &As[buf][c << 3]);
    }
#pragma unroll
    for (int i = 0; i < 4; ++i) {
      const int c = i * 512 + tid;
      const int r = c >> 3;
      const int cbs = ((c & 7) ^ (r & 7)) << 3;
      const int r64 = r & 63;
      const int rB = (r & 192) | ((r64 & 15) << 2) | (r64 >> 4);
      gload16(Bt + (size_t)(col0 + rB) * lda + k0 + cbs, &Bs[buf][c << 3]);
    }
  };
  auto COMPUTE = [&](int buf) {
    bfv8 bc[2][4];
#pragma unroll
    for (int kk = 0; kk < 2; ++kk)
#pragma unroll
      for (int nr = 0; nr < 4; ++nr) {
        const int br = (wn << 6) + (nr << 4) + lc;
        const int sl = ((kk << 2) | (lane >> 4)) ^ (br & 7);
        bc[kk][nr] = *reinterpret_cast<const bfv8*>(&Bs[buf][br * 64 + (sl << 3)]);
      }
#pragma unroll
    for (int mr = 0; mr < 8; ++mr) {
      const int ar = (wm << 7) + (mr << 4) + lc;
      const int sl0 = (lane >> 4) ^ (ar & 7);
      const int sl1 = (4 | (lane >> 4)) ^ (ar & 7);
      bfv8 a0 = *reinterpret_cast<const bfv8*>(&As[buf][ar * 64 + (sl0 << 3)]);
      bfv8 a1 = *reinterpret_cast<const bfv8*>(&As[buf][ar * 64 + (sl1 << 3)]);
#pragma unroll
      for (int nr = 0; nr < 4; ++nr) {
        acc[mr][nr] = __builtin_amdgcn_mfma_f32_16x16x32_bf16(a0, bc[0][nr], acc[mr][nr], 0, 0, 0);
        acc[mr][nr] = __builtin_amdgcn_mfma_f32_16x16x32_bf16(a1, bc[1][nr], acc[mr][nr], 0, 0, 0);
      }
    }
  };

  STAGE(0, 0);
  int cur = 0;
  for (int k0 = 0; k0 < K; k0 += 64) {
    if (k0 + 64 < K) {
      STAGE(cur ^ 1, k0 + 64);
      asm volatile("s_waitcnt vmcnt(8)" ::: "memory");
    } else {
      asm volatile("s_waitcnt vmcnt(0)" ::: "memory");
    }
    __builtin_amdgcn_s_barrier();
    __builtin_amdgcn_sched_barrier(0);
    COMPUTE(cur);
    __builtin_amdgcn_s_barrier();
    cur ^= 1;
  }

  const int gcb = col0 + (wn << 6) + (lc << 2);
#pragma unroll
  for (int mr = 0; mr < 8; ++mr) {
#pragma unroll
    for (int r = 0; r < 4; ++r) {
      const int gr = row0 + (wm << 7) + (mr << 4) + ((lane >> 4) << 2) + r;
      float t[4];
#pragma unroll
      for (int nr = 0; nr < 4; ++nr)
        t[nr] = acc[mr][nr][r] * ((gcb + nr) < acol ? alpha0 : alpha1);
      if constexpr (ROT) {
        if (col0 < 1024) {  // kk half only (block-uniform)
          const int j = gr & 127;
          const int cc = gcb & 63;
          float4 c4 = *reinterpret_cast<const float4*>(tab + j * 64 + cc);
          float4 s4 = *reinterpret_cast<const float4*>(tab + 8192 + j * 64 + cc);
          const float cs[4] = {c4.x, c4.y, c4.z, c4.w};
          const float sn[4] = {s4.x, s4.y, s4.z, s4.w};
          float o2[4];
#pragma unroll
          for (int nr = 0; nr < 4; ++nr) {
            const float pv = __shfl_xor(t[nr], 8);
            const float part = (cc < 32) ? -pv : pv;
            o2[nr] = t[nr] * cs[nr] + part * sn[nr];
          }
#pragma unroll
          for (int nr = 0; nr < 4; ++nr) t[nr] = o2[nr];
        }
      }
      if constexpr (HASBIAS) {
        float4 b4 = *reinterpret_cast<const float4*>(bias + gcb);
        t[0] += b4.x; t[1] += b4.y; t[2] += b4.z; t[3] += b4.w;
      }
      if constexpr (DOGELU) {
#pragma unroll
        for (int nr = 0; nr < 4; ++nr) {
          const float x = t[nr];
          t[nr] = 0.5f * x * (1.f + tanhf(0.7978845608f * (x + 0.044715f * x * x * x)));
        }
      }
      const size_t cb = (size_t)gr * ldc + coff + gcb;
      if constexpr (OT == 0) {
        *reinterpret_cast<float4*>((float*)C + cb) = make_float4(t[0], t[1], t[2], t[3]);
      } else {
        ushort4 o4 = {f2b(t[0]), f2b(t[1]), f2b(t[2]), f2b(t[3])};
        *reinterpret_cast<ushort4*>((u16*)C + cb) = o4;
      }
    }
  }
}

// ---------------------------------------------------------------------------
// 128x128 MFMA GEMM (verified): T1 col-major chunking (same rationale),
// T2 both-sides swizzle, packed epilogue, ROT, DBUF, split-K.
// ---------------------------------------------------------------------------
template <int OT, bool HASBIAS, bool HASRES, bool DOGELU, bool ROT, int DBUF, int PART>
__global__ __launch_bounds__(256) void mgemm_k(
    const u16* __restrict__ A, const u16* __restrict__ Bt, void* __restrict__ C,
    int M, int K, int lda, int ldc, int coff, float alpha0, float alpha1, int acol,
    const float* __restrict__ bias, const float* __restrict__ res,
    const float* __restrict__ tab) {
  constexpr int NBUF = DBUF ? 2 : 1;
  __shared__ u16 As[NBUF][128 * 64];
  __shared__ u16 Bs[NBUF][128 * 64];
  const int tid = threadIdx.x;
  const int w = tid >> 6, lane = tid & 63;
  const int wr = w >> 1, wc = w & 1;
  const int koff = blockIdx.z * K;

  const int nwg = gridDim.x * gridDim.y;
  const int bid = blockIdx.y * gridDim.x + blockIdx.x;
  const int qq = nwg >> 3, r8 = nwg & 7;
  const int xcd = bid & 7, pos = bid >> 3;
  const int cbase = (xcd < r8) ? xcd * (qq + 1) : r8 * (qq + 1) + (xcd - r8) * qq;
  const int logical = cbase + pos;
  const int row0 = (logical % gridDim.y) << 7;
  const int col0 = (logical / gridDim.y) << 7;

  f32x4 acc[4][4] = {};

  auto STAGE = [&](int buf, int k0) {
#pragma unroll
    for (int i = 0; i < 4; ++i) {
      const int c = ((w << 2) + i) * 64 + lane;
      const int r = c >> 3;
      const int cbs = ((c & 7) ^ (r & 7)) << 3;
      const int r64 = r & 63;
      const int rB = (r & 64) | ((r64 & 15) << 2) | (r64 >> 4);
      gload16(A + (size_t)(row0 + r) * lda + koff + k0 + cbs, &As[buf][((w << 2) + i) << 9]);
      gload16(Bt + (size_t)(col0 + rB) * lda + koff + k0 + cbs, &Bs[buf][((w << 2) + i) << 9]);
    }
  };
  auto COMPUTE = [&](int buf) {
#pragma unroll
    for (int kk = 0; kk < 2; ++kk) {
      bfv8 af[4], bfr[4];
#pragma unroll
      for (int m = 0; m < 4; ++m) {
        const int ar = (wr << 6) + (m << 4) + (lane & 15);
        const int sl = ((kk << 2) | (lane >> 4)) ^ (ar & 7);
        af[m] = *reinterpret_cast<const bfv8*>(&As[buf][ar * 64 + (sl << 3)]);
      }
#pragma unroll
      for (int n = 0; n < 4; ++n) {
        const int br = (wc << 6) + (n << 4) + (lane & 15);
        const int sl = ((kk << 2) | (lane >> 4)) ^ (br & 7);
        bfr[n] = *reinterpret_cast<const bfv8*>(&Bs[buf][br * 64 + (sl << 3)]);
      }
#pragma unroll
      for (int m = 0; m < 4; ++m)
#pragma unroll
        for (int n = 0; n < 4; ++n)
          acc[m][n] = __builtin_amdgcn_mfma_f32_16x16x32_bf16(af[m], bfr[n], acc[m][n], 0, 0, 0);
    }
  };

  if constexpr (DBUF) {
    STAGE(0, 0);
    int cur = 0;
    for (int k0 = 0; k0 < K; k0 += 64) {
      if (k0 + 64 < K) {
        STAGE(cur ^ 1, k0 + 64);
        asm volatile("s_waitcnt vmcnt(8)" ::: "memory");
      } else {
        asm volatile("s_waitcnt vmcnt(0)" ::: "memory");
      }
      __builtin_amdgcn_s_barrier();
      __builtin_amdgcn_sched_barrier(0);
      COMPUTE(cur);
      __builtin_amdgcn_s_barrier();
      cur ^= 1;
    }
  } else {
    for (int k0 = 0; k0 < K; k0 += 64) {
      STAGE(0, k0);
      __syncthreads();
      COMPUTE(0);
      __syncthreads();
    }
  }

  const int lr = (lane >> 4) << 2;
  const int lc = lane & 15;
  const int gcb = col0 + (wc << 6) + (lc << 2);
#pragma unroll
  for (int m = 0; m < 4; ++m) {
#pragma unroll
    for (int r = 0; r < 4; ++r) {
      const int gr = row0 + (wr << 6) + (m << 4) + lr + r;
      float t[4];
#pragma unroll
      for (int n = 0; n < 4; ++n)
        t[n] = acc[m][n][r] * ((gcb + n) < acol ? alpha0 : alpha1);
      if constexpr (ROT) {
        const int j = gr & 127;
        const int cc = gcb & 63;
        float4 c4 = *reinterpret_cast<const float4*>(tab + j * 64 + cc);
        float4 s4 = *reinterpret_cast<const float4*>(tab + 8192 + j * 64 + cc);
        const float cs[4] = {c4.x, c4.y, c4.z, c4.w};
        const float sn[4] = {s4.x, s4.y, s4.z, s4.w};
        float o2[4];
#pragma unroll
        for (int n = 0; n < 4; ++n) {
          const float pv = __shfl_xor(t[n], 8);
          const float part = (cc < 32) ? -pv : pv;
          o2[n] = t[n] * cs[n] + part * sn[n];
        }
#pragma unroll
        for (int n = 0; n < 4; ++n) t[n] = o2[n];
      }
      if constexpr (HASBIAS) {
        float4 b4 = *reinterpret_cast<const float4*>(bias + gcb);
        t[0] += b4.x; t[1] += b4.y; t[2] += b4.z; t[3] += b4.w;
      }
      if constexpr (DOGELU) {
#pragma unroll
        for (int n = 0; n < 4; ++n) {
          const float x = t[n];
          t[n] = 0.5f * x * (1.f + tanhf(0.7978845608f * (x + 0.044715f * x * x * x)));
        }
      }
      size_t cb = (size_t)gr * ldc + coff + gcb;
      if constexpr (PART) cb += (size_t)blockIdx.z * M * ldc;
      if constexpr (HASRES) {
        float4 r4 = *reinterpret_cast<const float4*>(res + cb);
        t[0] += r4.x; t[1] += r4.y; t[2] += r4.z; t[3] += r4.w;
      }
      if constexpr (OT == 0) {
        float4 o4 = make_float4(t[0], t[1], t[2], t[3]);
        *reinterpret_cast<float4*>((float*)C + cb) = o4;
      } else {
        ushort4 o4 = {f2b(t[0]), f2b(t[1]), f2b(t[2]), f2b(t[3])};
        *reinterpret_cast<ushort4*>((u16*)C + cb) = o4;
      }
    }
  }
}

// split-K reduce: out = p0 + p1 + bias + res   (f32, 4096x1024)
__global__ __launch_bounds__(256) void reduce_k(const float* __restrict__ p,
                                                const float* __restrict__ bias,
                                                const float* __restrict__ res,
                                                float* __restrict__ out) {
  const int i = blockIdx.x * 256 + threadIdx.x;
  const int col = (i & 255) << 2;
  float4 a = reinterpret_cast<const float4*>(p)[i];
  float4 b = reinterpret_cast<const float4*>(p + (size_t)4096 * 1024)[i];
  float4 b4 = *reinterpret_cast<const float4*>(bias + col);
  float4 r4 = reinterpret_cast<const float4*>(res)[i];
  float4 o;
  o.x = a.x + b.x + b4.x + r4.x;
  o.y = a.y + b.y + b4.y + r4.y;
  o.z = a.z + b.z + b4.z + r4.z;
  o.w = a.w + b.w + b4.w + r4.w;
  reinterpret_cast<float4*>(out)[i] = o;
}

// cos/sin table for kk rotary
__global__ __launch_bounds__(256) void costab_k(const float* __restrict__ kpe,
                                                float* __restrict__ tab) {
  const int i = blockIdx.x * 256 + threadIdx.x;
  const float f = kpe[i];
  tab[i] = cosf(f);
  tab[8192 + i] = sinf(f);
}

// batched weight transpose: 8x (f32 [1024,1024] -> bf16 [1024,1024]^T)
struct WtArgs {
  const float* in[8];
  u16* out[8];
};
__global__ __launch_bounds__(256) void wtrans8_k(WtArgs a) {
  const float* in = a.in[blockIdx.z];
  u16* out = a.out[blockIdx.z];
  __shared__ float t[32][33];
  const int tx = threadIdx.x & 31, ty = threadIdx.x >> 5;
  const int r0 = blockIdx.y << 5, c0 = blockIdx.x << 5;
#pragma unroll
  for (int i = 0; i < 4; ++i)
    t[ty + 8 * i][tx] = in[(size_t)(r0 + ty + 8 * i) * 1024 + c0 + tx];
  __syncthreads();
#pragma unroll
  for (int i = 0; i < 4; ++i)
    out[(size_t)(c0 + ty + 8 * i) * 1024 + r0 + tx] = f2b(t[tx][ty + 8 * i]);
}

// generic weight transpose (W1/W2): f32 [K,N] -> bf16 [N,K]
__global__ __launch_bounds__(256) void wtrans_k(const float* __restrict__ in,
                                                u16* __restrict__ out, int K, int N) {
  __shared__ float t[32][33];
  const int tx = threadIdx.x & 31, ty = threadIdx.x >> 5;
  const int r0 = blockIdx.y << 5, c0 = blockIdx.x << 5;
#pragma unroll
  for (int i = 0; i < 4; ++i)
    t[ty + 8 * i][tx] = in[(size_t)(r0 + ty + 8 * i) * N + c0 + tx];
  __syncthreads();
#pragma unroll
  for (int i = 0; i < 4; ++i)
    out[(size_t)(c0 + ty + 8 * i) * K + r0 + tx] = f2b(t[tx][ty + 8 * i]);
}

// flat f32 -> bf16 cast
__global__ __launch_bounds__(256) void cast_k(const float* __restrict__ in,
                                              u16* __restrict__ out) {
  const int i = blockIdx.x * 256 + threadIdx.x;
  float4 v = reinterpret_cast<const float4*>(in)[i];
  ushort4 o = {f2b(v.x), f2b(v.y), f2b(v.z), f2b(v.w)};
  reinterpret_cast<ushort4*>(out)[i] = o;
}

// LayerNorm rows of 1024; f32 in, bf16 out (ln1)
__global__ __launch_bounds__(256) void ln_k(const float* __restrict__ in,
                                            const float* __restrict__ g,
                                            const float* __restrict__ b,
                                            u16* __restrict__ out) {
  const int tid = threadIdx.x;
  const int c = tid << 2;
  const size_t base = (size_t)blockIdx.x * DM;
  float4 x = *reinterpret_cast<const float4*>(in + base + c);
  float s = x.x + x.y + x.z + x.w;
  float ss = x.x * x.x + x.y * x.y + x.z * x.z + x.w * x.w;
#pragma unroll
  for (int m = 1; m < 64; m <<= 1) {
    s += __shfl_xor(s, m, 64);
    ss += __shfl_xor(ss, m, 64);
  }
  __shared__ float ls[4], lss[4];
  if ((tid & 63) == 0) { ls[tid >> 6] = s; lss[tid >> 6] = ss; }
  __syncthreads();
  s = (ls[0] + ls[1]) + (ls[2] + ls[3]);
  ss = (lss[0] + lss[1]) + (lss[2] + lss[3]);
  const float mu = s * (1.f / DM);
  const float var = ss * (1.f / DM) - mu * mu;
  const float rstd = rsqrtf(var + 1e-5f);
  float4 g4 = *reinterpret_cast<const float4*>(g + c);
  float4 b4 = *reinterpret_cast<const float4*>(b + c);
  ushort4 u;
  u.x = f2b((x.x - mu) * rstd * g4.x + b4.x);
  u.y = f2b((x.y - mu) * rstd * g4.y + b4.y);
  u.z = f2b((x.z - mu) * rstd * g4.z + b4.z);
  u.w = f2b((x.w - mu) * rstd * g4.w + b4.w);
  *reinterpret_cast<ushort4*>(out + base + c) = u;
}

// LN2 with fused xq-shift
__global__ __launch_bounds__(256) void ln2x_k(const float* __restrict__ in,
                                              const float* __restrict__ g,
                                              const float* __restrict__ b,
                                              float* __restrict__ hs,
                                              u16* __restrict__ xq) {
  const int tid = threadIdx.x;
  const int c = tid << 2;
  const int row = blockIdx.x;
  const size_t base = (size_t)row * DM;
  float4 x = *reinterpret_cast<const float4*>(in + base + c);
  float s = x.x + x.y + x.z + x.w;
  float ss = x.x * x.x + x.y * x.y + x.z * x.z + x.w * x.w;
#pragma unroll
  for (int m = 1; m < 64; m <<= 1) {
    s += __shfl_xor(s, m, 64);
    ss += __shfl_xor(ss, m, 64);
  }
  __shared__ float ls[4], lss[4];
  if ((tid & 63) == 0) { ls[tid >> 6] = s; lss[tid >> 6] = ss; }
  __syncthreads();
  s = (ls[0] + ls[1]) + (ls[2] + ls[3]);
  ss = (lss[0] + lss[1]) + (lss[2] + lss[3]);
  const float mu = s * (1.f / DM);
  const float var = ss * (1.f / DM) - mu * mu;
  const float rstd = rsqrtf(var + 1e-5f);
  float4 g4 = *reinterpret_cast<const float4*>(g + c);
  float4 b4 = *reinterpret_cast<const float4*>(b + c);
  float4 o;
  o.x = (x.x - mu) * rstd * g4.x + b4.x;
  o.y = (x.y - mu) * rstd * g4.y + b4.y;
  o.z = (x.z - mu) * rstd * g4.z + b4.z;
  o.w = (x.w - mu) * rstd * g4.w + b4.w;
  *reinterpret_cast<float4*>(hs + base + c) = o;
  const int local = row & (SEQ - 1);
  const int bb = row >> 10;
  if (local >= 63) {
    ushort4 u = {f2b(o.x), f2b(o.y), f2b(o.z), f2b(o.w)};
    *reinterpret_cast<ushort4*>(xq + (size_t)((bb << 10) + local - 63) * DM + c) = u;
  } else {
    ushort4 z = {0, 0, 0, 0};
    *reinterpret_cast<ushort4*>(xq + (size_t)((bb << 10) + 961 + local) * DM + c) = z;
  }
}

// t5norm(shift_right_63(cca_bf16) + hs_f32) * w -> bf16
__global__ __launch_bounds__(256) void t5_k(const u16* __restrict__ cca,
                                            const float* __restrict__ hs,
                                            const float* __restrict__ w,
                                            u16* __restrict__ out) {
  const int tid = threadIdx.x;
  const int row = blockIdx.x;
  const int t = row & (SEQ - 1);
  const int c = tid << 2;
  const size_t base = (size_t)row * DM;
  float4 x = *reinterpret_cast<const float4*>(hs + base + c);
  if (t >= 63) {
    ushort4 cu = *reinterpret_cast<const ushort4*>(cca + base - (size_t)63 * DM + c);
    x.x += u2f(cu.x); x.y += u2f(cu.y); x.z += u2f(cu.z); x.w += u2f(cu.w);
  }
  float ss = x.x * x.x + x.y * x.y + x.z * x.z + x.w * x.w;
#pragma unroll
  for (int m = 1; m < 64; m <<= 1) ss += __shfl_xor(ss, m, 64);
  __shared__ float lss[4];
  if ((tid & 63) == 0) lss[tid >> 6] = ss;
  __syncthreads();
  ss = (lss[0] + lss[1]) + (lss[2] + lss[3]);
  const float rms = sqrtf(ss * (1.f / DM));
  const float inv = 1.f / fmaxf(rms, 1e-6f);
  float4 w4 = *reinterpret_cast<const float4*>(w + c);
  ushort4 o = {f2b(x.x * inv * w4.x), f2b(x.y * inv * w4.y),
               f2b(x.z * inv * w4.z), f2b(x.w * inv * w4.w)};
  *reinterpret_cast<ushort4*>(out + base + c) = o;
}

// rotary on q_c: row 0 of each 64-row chunk, freqs qpe[63]
__global__ __launch_bounds__(256) void rotq_k(u16* __restrict__ q,
                                              const float* __restrict__ qpe) {
  __shared__ float rb[DM];
  const size_t base = (size_t)blockIdx.x * 64 * DM;
  const int e = threadIdx.x << 2;
  ushort4 u = *reinterpret_cast<const ushort4*>(q + base + e);
  rb[e + 0] = u2f(u.x); rb[e + 1] = u2f(u.y); rb[e + 2] = u2f(u.z); rb[e + 3] = u2f(u.w);
  __syncthreads();
  u16 ov[4];
#pragma unroll
  for (int k = 0; k < 4; ++k) {
    const int ee = e + k;
    const int cc = ee & 63;
    const float f = qpe[63 * 64 + cc];
    const float t1 = rb[ee];
    const float part = (cc < 32) ? -rb[ee + 32] : rb[ee - 32];
    ov[k] = f2b(t1 * cosf(f) + part * sinf(f));
  }
  ushort4 o = {ov[0], ov[1], ov[2], ov[3]};
  *reinterpret_cast<ushort4*>(q + base + e) = o;
}

// vt slot swizzle: physical slot = logical slot ^ ((d>>2)&7)
__device__ __forceinline__ int vswz(int d, int k) {
  return (k & 7) | (((k >> 3) ^ ((d >> 2) & 7)) << 3);
}

// ---------------------------------------------------------------------------
// MFMA causal self-attention, QB=128, 8 waves, pitch 88, balanced qt map.
// ---------------------------------------------------------------------------
__global__ __launch_bounds__(512) void attn_self_k(const u16* __restrict__ qkv,
                                                   u16* __restrict__ o) {
  const int h = blockIdx.y, b = blockIdx.z;
  const int qt = (blockIdx.z < 2) ? blockIdx.x : (7 - blockIdx.x);
  __shared__ u16 qs[128][88];
  __shared__ u16 ks[64][88];
  __shared__ u16 vt[64][88];
  __shared__ u16 ps[128][88];
  const int tid = threadIdx.x;
  const int w = tid >> 6, lane = tid & 63;
  const int strip = w << 4;
  const int sloc = (w & 3) << 4;
  const int lrow = lane & 15, lk = lane >> 4;
  const int rowb = b * SEQ;
  const int hoff = h * DHD;
  const int qrow0 = qt << 7;

#pragma unroll
  for (int rp = 0; rp < 4; ++rp) {
    const int fi = tid + (rp << 9);
    const int r = fi >> 4, c4 = (fi & 15) << 2;
    *reinterpret_cast<ushort4*>(&qs[r][c4]) =
        *reinterpret_cast<const ushort4*>(qkv + (size_t)(rowb + qrow0 + r) * 3072 + hoff + c4);
  }

  ushort4 kr[2], vr[2];
  auto loadKV = [&](int kt) {
#pragma unroll
    for (int rp = 0; rp < 2; ++rp) {
      const int fi = tid + (rp << 9);
      const int r = fi >> 4, c4 = (fi & 15) << 2;
      const size_t g = (size_t)(rowb + kt * 64 + r) * 3072 + hoff + c4;
      kr[rp] = *reinterpret_cast<const ushort4*>(qkv + g + 1024);
      vr[rp] = *reinterpret_cast<const ushort4*>(qkv + g + 2048);
    }
  };
  loadKV(0);

  const int ktmax = 2 * qt + 1;
  const int ktd = 2 * qt + (w >> 2);

  float mrun[4], lrun[4];
  f32x4 accO[4] = {};
#pragma unroll
  for (int r = 0; r < 4; ++r) { mrun[r] = -1e30f; lrun[r] = 0.f; }

  for (int kt = 0; kt <= ktmax; ++kt) {
    __syncthreads();
#pragma unroll
    for (int rp = 0; rp < 2; ++rp) {
      const int fi = tid + (rp << 9);
      const int r = fi >> 4, c4 = (fi & 15) << 2;
      *reinterpret_cast<ushort4*>(&ks[r][c4]) = kr[rp];
      vt[c4 + 0][vswz(c4 + 0, r)] = vr[rp].x;
      vt[c4 + 1][vswz(c4 + 1, r)] = vr[rp].y;
      vt[c4 + 2][vswz(c4 + 2, r)] = vr[rp].z;
      vt[c4 + 3][vswz(c4 + 3, r)] = vr[rp].w;
    }
    __syncthreads();
    if (kt < ktmax) loadKV(kt + 1);

    if (kt <= ktd) {
      f32x4 sacc[4] = {};
#pragma unroll
      for (int kk = 0; kk < 2; ++kk) {
        bfv8 qf = *reinterpret_cast<const bfv8*>(&qs[strip + lrow][(kk << 5) + (lk << 3)]);
#pragma unroll
        for (int n = 0; n < 4; ++n) {
          bfv8 kf = *reinterpret_cast<const bfv8*>(&ks[(n << 4) + lrow][(kk << 5) + (lk << 3)]);
          sacc[n] = __builtin_amdgcn_mfma_f32_16x16x32_bf16(qf, kf, sacc[n], 0, 0, 0);
        }
      }
      if (kt == ktd) {
#pragma unroll
        for (int n = 0; n < 4; ++n)
#pragma unroll
          for (int r = 0; r < 4; ++r)
            if ((n << 4) + lrow > sloc + (lk << 2) + r) sacc[n][r] = -1e30f;
      }
#pragma unroll
      for (int r = 0; r < 4; ++r) {
        float mt = fmaxf(fmaxf(sacc[0][r], sacc[1][r]), fmaxf(sacc[2][r], sacc[3][r]));
        mt = fmaxf(mt, __shfl_xor(mt, 1));
        mt = fmaxf(mt, __shfl_xor(mt, 2));
        mt = fmaxf(mt, __shfl_xor(mt, 4));
        mt = fmaxf(mt, __shfl_xor(mt, 8));
        const float nm = fmaxf(mrun[r], mt);
        const float f = __expf(mrun[r] - nm);
        mrun[r] = nm;
        float p0 = __expf(sacc[0][r] - nm);
        float p1 = __expf(sacc[1][r] - nm);
        float p2 = __expf(sacc[2][r] - nm);
        float p3 = __expf(sacc[3][r] - nm);
        float rs = (p0 + p1) + (p2 + p3);
        rs += __shfl_xor(rs, 1);
        rs += __shfl_xor(rs, 2);
        rs += __shfl_xor(rs, 4);
        rs += __shfl_xor(rs, 8);
        lrun[r] = lrun[r] * f + rs;
#pragma unroll
        for (int nd = 0; nd < 4; ++nd) accO[nd][r] *= f;
        const int prow = strip + (lk << 2) + r;
        ps[prow][lrow +  0] = f2b(p0);
        ps[prow][lrow + 16] = f2b(p1);
        ps[prow][lrow + 32] = f2b(p2);
        ps[prow][lrow + 48] = f2b(p3);
      }
#pragma unroll
      for (int kk = 0; kk < 2; ++kk) {
        bfv8 pf = *reinterpret_cast<const bfv8*>(&ps[strip + lrow][(kk << 5) + (lk << 3)]);
#pragma unroll
        for (int nd = 0; nd < 4; ++nd) {
          const int vd = (nd << 4) + lrow;
          const int slot = ((kk << 2) | lk) ^ ((vd >> 2) & 7);
          bfv8 vf = *reinterpret_cast<const bfv8*>(&vt[vd][slot << 3]);
          accO[nd] = __builtin_amdgcn_mfma_f32_16x16x32_bf16(pf, vf, accO[nd], 0, 0, 0);
        }
      }
    }
  }
#pragma unroll
  for (int r = 0; r < 4; ++r) {
    const float inv = 1.f / lrun[r];
    const size_t rowoff = (size_t)(rowb + qrow0 + strip + (lk << 2) + r) * DM + hoff;
#pragma unroll
    for (int nd = 0; nd < 4; ++nd)
      o[rowoff + (nd << 4) + lrow] = f2b(accO[nd][r] * inv);
  }
}

// ---------------------------------------------------------------------------
// MFMA chunked cross-attention: 257 keys, kk/vv fused [16384][2048]. Pitch 88.
// ---------------------------------------------------------------------------
__global__ __launch_bounds__(256) void attn_cca_k(
    const u16* __restrict__ q, const u16* __restrict__ kv,
    const float* __restrict__ nullk, const float* __restrict__ nullv,
    u16* __restrict__ o) {
  const int h = blockIdx.y, bk = blockIdx.z;
  __shared__ u16 qs[64][88];
  __shared__ u16 ks[64][88];
  __shared__ u16 vt[64][88];
  __shared__ u16 ps[64][88];
  const int tid = threadIdx.x;
  const int w = tid >> 6, lane = tid & 63;
  const int strip = w << 4;
  const int lrow = lane & 15, lk = lane >> 4;
  const int hoff = h * DHD;
  const size_t qbase = (size_t)bk * 64 * DM + hoff;

#pragma unroll
  for (int rp = 0; rp < 4; ++rp) {
    const int fi = tid + (rp << 8);
    const int r = fi >> 4, c4 = (fi & 15) << 2;
    *reinterpret_cast<ushort4*>(&qs[r][c4]) =
        *reinterpret_cast<const ushort4*>(q + qbase + (size_t)r * DM + c4);
  }

  ushort4 kr[4], vr[4];
  auto loadKV = [&](int kt) {
#pragma unroll
    for (int rp = 0; rp < 4; ++rp) {
      const int fi = tid + (rp << 8);
      const int r = fi >> 4, c4 = (fi & 15) << 2;
      const int kj = kt * 64 + r;
      ushort4 ku = {0, 0, 0, 0}, vu = {0, 0, 0, 0};
      if (kj == 0) {
        float4 nk4 = *reinterpret_cast<const float4*>(nullk + hoff + c4);
        float4 nv4 = *reinterpret_cast<const float4*>(nullv + hoff + c4);
        ku = {f2b(nk4.x), f2b(nk4.y), f2b(nk4.z), f2b(nk4.w)};
        vu = {f2b(nv4.x), f2b(nv4.y), f2b(nv4.z), f2b(nv4.w)};
      } else if (kj <= 256) {
        const size_t g = (size_t)(bk * 256 + kj - 1) * 2048 + hoff + c4;
        ku = *reinterpret_cast<const ushort4*>(kv + g);
        vu = *reinterpret_cast<const ushort4*>(kv + g + 1024);
      }
      kr[rp] = ku; vr[rp] = vu;
    }
  };
  loadKV(0);

  float mrun[4], lrun[4];
  f32x4 accO[4] = {};
#pragma unroll
  for (int r = 0; r < 4; ++r) { mrun[r] = -1e30f; lrun[r] = 0.f; }

  for (int kt = 0; kt < 5; ++kt) {
    __syncthreads();
#pragma unroll
    for (int rp = 0; rp < 4; ++rp) {
      const int fi = tid + (rp << 8);
      const int r = fi >> 4, c4 = (fi & 15) << 2;
      *reinterpret_cast<ushort4*>(&ks[r][c4]) = kr[rp];
      vt[c4 + 0][vswz(c4 + 0, r)] = vr[rp].x;
      vt[c4 + 1][vswz(c4 + 1, r)] = vr[rp].y;
      vt[c4 + 2][vswz(c4 + 2, r)] = vr[rp].z;
      vt[c4 + 3][vswz(c4 + 3, r)] = vr[rp].w;
    }
    __syncthreads();
    if (kt < 4) loadKV(kt + 1);

    f32x4 sacc[4] = {};
#pragma unroll
    for (int kk = 0; kk < 2; ++kk) {
      bfv8 qf = *reinterpret_cast<const bfv8*>(&qs[strip + lrow][(kk << 5) + (lk << 3)]);
#pragma unroll
      for (int n = 0; n < 4; ++n) {
        bfv8 kf = *reinterpret_cast<const bfv8*>(&ks[(n << 4) + lrow][(kk << 5) + (lk << 3)]);
        sacc[n] = __builtin_amdgcn_mfma_f32_16x16x32_bf16(qf, kf, sacc[n], 0, 0, 0);
      }
    }
    if (kt == 4) {
#pragma unroll
      for (int n = 0; n < 4; ++n)
#pragma unroll
        for (int r = 0; r < 4; ++r)
          if ((n << 4) + lrow >= 1) sacc[n][r] = -1e30f;
    }
#pragma unroll
    for (int r = 0; r < 4; ++r) {
      float mt = fmaxf(fmaxf(sacc[0][r], sacc[1][r]), fmaxf(sacc[2][r], sacc[3][r]));
      mt = fmaxf(mt, __shfl_xor(mt, 1));
      mt = fmaxf(mt, __shfl_xor(mt, 2));
      mt = fmaxf(mt, __shfl_xor(mt, 4));
      mt = fmaxf(mt, __shfl_xor(mt, 8));
      const float nm = fmaxf(mrun[r], mt);
      const float f = __expf(mrun[r] - nm);
      mrun[r] = nm;
      float p0 = __expf(sacc[0][r] - nm);
      float p1 = __expf(sacc[1][r] - nm);
      float p2 = __expf(sacc[2][r] - nm);
      float p3 = __expf(sacc[3][r] - nm);
      float rs = (p0 + p1) + (p2 + p3);
      rs += __shfl_xor(rs, 1);
      rs += __shfl_xor(rs, 2);
      rs += __shfl_xor(rs, 4);
      rs += __shfl_xor(rs, 8);
      lrun[r] = lrun[r] * f + rs;
#pragma unroll
      for (int nd = 0; nd < 4; ++nd) accO[nd][r] *= f;
      const int prow = strip + (lk << 2) + r;
      ps[prow][lrow +  0] = f2b(p0);
      ps[prow][lrow + 16] = f2b(p1);
      ps[prow][lrow + 32] = f2b(p2);
      ps[prow][lrow + 48] = f2b(p3);
    }
#pragma unroll
    for (int kk = 0; kk < 2; ++kk) {
      bfv8 pf = *reinterpret_cast<const bfv8*>(&ps[strip + lrow][(kk << 5) + (lk << 3)]);
#pragma unroll
      for (int nd = 0; nd < 4; ++nd) {
        const int vd = (nd << 4) + lrow;
        const int slot = ((kk << 2) | lk) ^ ((vd >> 2) & 7);
        bfv8 vf = *reinterpret_cast<const bfv8*>(&vt[vd][slot << 3]);
        accO[nd] = __builtin_amdgcn_mfma_f32_16x16x32_bf16(pf, vf, accO[nd], 0, 0, 0);
      }
    }
  }
#pragma unroll
  for (int r = 0; r < 4; ++r) {
    const float inv = 1.f / lrun[r];
    const size_t rowoff = (size_t)(bk * 64 + strip + (lk << 2) + r) * DM + hoff;
#pragma unroll
    for (int nd = 0; nd < 4; ++nd)
      o[rowoff + (nd << 4) + lrow] = f2b(accO[nd][r] * inv);
  }
}

// ---------------------------------------------------------------------------
extern "C" void kernel_launch(void* const* d_in, const int* in_sizes, int n_in,
                              void* d_out, int out_size, void* d_ws, size_t ws_size,
                              hipStream_t stream) {
  const float* hidden    = (const float*)d_in[0];
  const float* retrieval = (const float*)d_in[1];
  const float* q_pos     = (const float*)d_in[2];
  const float* k_pos     = (const float*)d_in[3];
  const float* ln1_g     = (const float*)d_in[4];
  const float* ln1_b     = (const float*)d_in[5];
  const float* Wq_s      = (const float*)d_in[6];
  const float* Wk_s      = (const float*)d_in[7];
  const float* Wv_s      = (const float*)d_in[8];
  const float* Wo_s      = (const float*)d_in[9];
  const float* bo_s      = (const float*)d_in[10];
  const float* ln2_g     = (const float*)d_in[11];
  const float* ln2_b     = (const float*)d_in[12];
  const float* Wq_c      = (const float*)d_in[13];
  const float* Wk_c      = (const float*)d_in[14];
  const float* Wv_c      = (const float*)d_in[15];
  const float* Wo_c      = (const float*)d_in[16];
  const float* bo_c      = (const float*)d_in[17];
  const float* null_k    = (const float*)d_in[18];
  const float* null_v    = (const float*)d_in[19];
  const float* post_w    = (const float*)d_in[20];
  const float* W1        = (const float*)d_in[21];
  const float* b1        = (const float*)d_in[22];
  const float* W2        = (const float*)d_in[23];
  const float* b2        = (const float*)d_in[24];
  float* out = (float*)d_out;

  constexpr size_t MB = 1024 * 1024;
  constexpr size_t ME = 1024 * 1024;
  char* W = (char*)d_ws;
  u16* Wt_qkv  = (u16*)(W + 0 * MB);    // [3072][1024] 6MB
  u16* Wt_os   = (u16*)(W + 6 * MB);    // 2MB
  u16* Wt_qc   = (u16*)(W + 8 * MB);    // 2MB
  u16* Wt_kcvc = (u16*)(W + 10 * MB);   // [2048][1024] 4MB
  u16* Wt_oc   = (u16*)(W + 14 * MB);   // 2MB
  u16* W1t     = (u16*)(W + 16 * MB);   // [4096][1024] 8MB
  u16* W2t     = (u16*)(W + 24 * MB);   // [1024][4096] 8MB
  float* s5    = (float*)(W + 32 * MB); // hs f32, 16MB [persist]
  float* s0    = (float*)(W + 48 * MB); // f32 16MB    [5-6]
  u16* retb    = (u16*)(W + 48 * MB);   // 32MB        [7-9]
  u16* ccab    = (u16*)(W + 48 * MB);   // 8MB         [10-11]
  u16* ccapb   = (u16*)(W + 56 * MB);   // 8MB         [11-12]
  u16* xb      = (u16*)(W + 64 * MB);   // 8MB         [2-3]
  u16* t5b     = (u16*)(W + 64 * MB);   // 8MB         [12-13]
  u16* attnb   = (u16*)(W + 80 * MB);   // 8MB         [4-5]
  u16* xqb     = (u16*)(W + 80 * MB);   // 8MB         [6-8]
  float* tab   = (float*)(W + 80 * MB); // 64KB        [8.5-9]
  u16* qkvb    = (u16*)(W + 88 * MB);   // 24MB        [3-4]
  u16* qcb     = (u16*)(W + 88 * MB);   // 8MB         [8-10]
  u16* kkvvb   = (u16*)(W + 96 * MB);   // 64MB        [9-10]
  u16* ff1b    = (u16*)(W + 96 * MB);   // 32MB        [13-14]
  float* fpart = (float*)(W + 128 * MB);// 2x16MB f32  [14]

  const dim3 blk(256);

  WtArgs wa;
  wa.in[0] = Wq_s; wa.out[0] = Wt_qkv + 0 * ME;
  wa.in[1] = Wk_s; wa.out[1] = Wt_qkv + 1 * ME;
  wa.in[2] = Wv_s; wa.out[2] = Wt_qkv + 2 * ME;
  wa.in[3] = Wo_s; wa.out[3] = Wt_os;
  wa.in[4] = Wq_c; wa.out[4] = Wt_qc;
  wa.in[5] = Wk_c; wa.out[5] = Wt_kcvc + 0 * ME;
  wa.in[6] = Wv_c; wa.out[6] = Wt_kcvc + 1 * ME;
  wa.in[7] = Wo_c; wa.out[7] = Wt_oc;
  wtrans8_k<<<dim3(32, 32, 8), blk, 0, stream>>>(wa);
  wtrans_k<<<dim3(128, 32), blk, 0, stream>>>(W1, W1t, 1024, 4096);
  wtrans_k<<<dim3(32, 128), blk, 0, stream>>>(W2, W2t, 4096, 1024);

  // 2. ln1 -> xb
  ln_k<<<dim3(4096), blk, 0, stream>>>(hidden, ln1_g, ln1_b, xb);
  // 3. fused qkv projection (256^2 tile)
  mgemm256_k<1, false, false, false><<<dim3(12, 16), dim3(512), 0, stream>>>(
      xb, Wt_qkv, qkvb, 4096, 1024, 1024, 3072, 0, 0.125f, 1.f, 1024, nullptr, nullptr);
  // 4. causal self-attention (QB=128, 8 waves, balanced qt map)
  attn_self_k<<<dim3(8, 16, 4), dim3(512), 0, stream>>>(qkvb, attnb);
  // 5. o-proj + residual (DBUF 128^2)
  mgemm_k<0, true, true, false, false, 1, 0><<<dim3(8, 32), blk, 0, stream>>>(
      attnb, Wt_os, s0, 4096, 1024, 1024, 1024, 0, 1.f, 1.f, 0, bo_s, hidden, nullptr);
  // 6. ln2 -> s5 + xqb
  ln2x_k<<<dim3(4096), blk, 0, stream>>>(s0, ln2_g, ln2_b, s5, xqb);
  // 7. cast retrieval
  cast_k<<<dim3(16384), blk, 0, stream>>>(retrieval, retb);
  // 8. q_c projection (DBUF 128^2)
  mgemm_k<1, false, false, false, false, 1, 0><<<dim3(8, 32), blk, 0, stream>>>(
      xqb, Wt_qc, qcb, 4096, 1024, 1024, 1024, 0, 1.f, 0.125f, 0, nullptr, nullptr, nullptr);
  rotq_k<<<dim3(64), blk, 0, stream>>>(qcb, q_pos);
  // 8.5 cos/sin table
  costab_k<<<dim3(32), blk, 0, stream>>>(k_pos, tab);
  // 9. fused kk|vv projection, one N=2048 launch; rotary on kk half only
  mgemm256_k<1, false, false, true><<<dim3(8, 64), dim3(512), 0, stream>>>(
      retb, Wt_kcvc, kkvvb, 16384, 1024, 1024, 2048, 0, 1.f, 1.f, 0, nullptr, tab);
  // 10. cross attention
  attn_cca_k<<<dim3(1, 16, 64), blk, 0, stream>>>(qcb, kkvvb, null_k, null_v, ccab);
  // 11. cca projection (DBUF 128^2)
  mgemm_k<1, true, false, false, false, 1, 0><<<dim3(8, 32), blk, 0, stream>>>(
      ccab, Wt_oc, ccapb, 4096, 1024, 1024, 1024, 0, 1.f, 1.f, 0, bo_c, nullptr, nullptr);
  // 12. t5norm
  t5_k<<<dim3(4096), blk, 0, stream>>>(ccapb, s5, post_w, t5b);
  // 13. FFN1 (256^2 tile, gelu)
  mgemm256_k<1, true, true, false><<<dim3(16, 16), dim3(512), 0, stream>>>(
      t5b, W1t, ff1b, 4096, 1024, 1024, 4096, 0, 1.f, 1.f, 0, b1, nullptr);
  // 14. FFN2 split-K=2 -> f32 partials (DBUF 128^2)
  mgemm_k<0, false, false, false, false, 1, 1><<<dim3(8, 32, 2), blk, 0, stream>>>(
      ff1b, W2t, fpart, 4096, 2048, 4096, 1024, 0, 1.f, 1.f, 0, nullptr, nullptr, nullptr);
  // 14b. reduce partials + bias + residual -> out
  reduce_k<<<dim3(4096), blk, 0, stream>>>(fpart, b2, s5, out);
}

// Round 15
// 407.358 us; speedup vs baseline: 1.0545x; 1.0545x over previous
//
#include <hip/hip_runtime.h>
#include <hip/hip_bf16.h>
#include <math.h>

using u16 = unsigned short;

static constexpr int SEQ = 1024;
static constexpr int DM  = 1024;
static constexpr int DHD = 64;

typedef __bf16 bfv8 __attribute__((ext_vector_type(8)));
typedef float  f32x4 __attribute__((ext_vector_type(4)));

__device__ __forceinline__ float u2f(u16 u) {
  return __uint_as_float(((unsigned int)u) << 16);
}
__device__ __forceinline__ u16 f2b(float x) {
  __hip_bfloat16 h = __float2bfloat16(x);
  return *reinterpret_cast<u16*>(&h);
}
__device__ __forceinline__ void gload16(const u16* g, u16* l) {
  __builtin_amdgcn_global_load_lds(
      (const __attribute__((address_space(1))) unsigned int*)g,
      (__attribute__((address_space(3))) unsigned int*)l, 16, 0, 0);
}

// ---------------------------------------------------------------------------
// 256x256-tile MFMA GEMM, 8 waves, BK=64, DBUF 128KB LDS.
// T1 ROW-major chunking (round-13 verified best): each XCD owns contiguous
// row-panels -> A-slab reuse in its private L2 (FETCH ~ideal); B (<=4MB)
// served via L3. [Round-14 col-major variant pushed all A traffic to L3:
// FETCH 50->135MB, time +12% -- reverted.]
// ROT applied only to blocks with col0 < 1024 (block-uniform).
// ---------------------------------------------------------------------------
template <int OT, bool HASBIAS, bool DOGELU, bool ROT>
__global__ __launch_bounds__(512) void mgemm256_k(
    const u16* __restrict__ A, const u16* __restrict__ Bt, void* __restrict__ C,
    int M, int K, int lda, int ldc, int coff, float alpha0, float alpha1, int acol,
    const float* __restrict__ bias, const float* __restrict__ tab) {
  __shared__ u16 As[2][256 * 64];
  __shared__ u16 Bs[2][256 * 64];
  const int tid = threadIdx.x;
  const int w = tid >> 6, lane = tid & 63;
  const int wm = w >> 2, wn = w & 3;
  const int lc = lane & 15;

  const int nwg = gridDim.x * gridDim.y;
  const int bid = blockIdx.y * gridDim.x + blockIdx.x;
  const int qq = nwg >> 3, r8 = nwg & 7;
  const int xcd = bid & 7, pos = bid >> 3;
  const int cbase = (xcd < r8) ? xcd * (qq + 1) : r8 * (qq + 1) + (xcd - r8) * qq;
  const int logical = cbase + pos;
  const int row0 = (logical / gridDim.x) << 8;
  const int col0 = (logical % gridDim.x) << 8;

  f32x4 acc[8][4] = {};

  auto STAGE = [&](int buf, int k0) {
#pragma unroll
    for (int i = 0; i < 4; ++i) {
      const int c = i * 512 + tid;
      const int r = c >> 3;
      const int cbs = ((c & 7) ^ (r & 7)) << 3;
      gload16(A + (size_t)(row0 + r) * lda + k0 + cbs, &As[buf][c << 3]);
    }
#pragma unroll
    for (int i = 0; i < 4; ++i) {
      const int c = i * 512 + tid;
      const int r = c >> 3;
      const int cbs = ((c & 7) ^ (r & 7)) << 3;
      const int r64 = r & 63;
      const int rB = (r & 192) | ((r64 & 15) << 2) | (r64 >> 4);
      gload16(Bt + (size_t)(col0 + rB) * lda + k0 + cbs, &Bs[buf][c << 3]);
    }
  };
  auto COMPUTE = [&](int buf) {
    bfv8 bc[2][4];
#pragma unroll
    for (int kk = 0; kk < 2; ++kk)
#pragma unroll
      for (int nr = 0; nr < 4; ++nr) {
        const int br = (wn << 6) + (nr << 4) + lc;
        const int sl = ((kk << 2) | (lane >> 4)) ^ (br & 7);
        bc[kk][nr] = *reinterpret_cast<const bfv8*>(&Bs[buf][br * 64 + (sl << 3)]);
      }
#pragma unroll
    for (int mr = 0; mr < 8; ++mr) {
      const int ar = (wm << 7) + (mr << 4) + lc;
      const int sl0 = (lane >> 4) ^ (ar & 7);
      const int sl1 = (4 | (lane >> 4)) ^ (ar & 7);
      bfv8 a0 = *reinterpret_cast<const bfv8*>(&As[buf][ar * 64 + (sl0 << 3)]);
      bfv8 a1 = *reinterpret_cast<const bfv8*>(&As[buf][ar * 64 + (sl1 << 3)]);
#pragma unroll
      for (int nr = 0; nr < 4; ++nr) {
        acc[mr][nr] = __builtin_amdgcn_mfma_f32_16x16x32_bf16(a0, bc[0][nr], acc[mr][nr], 0, 0, 0);
        acc[mr][nr] = __builtin_amdgcn_mfma_f32_16x16x32_bf16(a1, bc[1][nr], acc[mr][nr], 0, 0, 0);
      }
    }
  };

  STAGE(0, 0);
  int cur = 0;
  for (int k0 = 0; k0 < K; k0 += 64) {
    if (k0 + 64 < K) {
      STAGE(cur ^ 1, k0 + 64);
      asm volatile("s_waitcnt vmcnt(8)" ::: "memory");
    } else {
      asm volatile("s_waitcnt vmcnt(0)" ::: "memory");
    }
    __builtin_amdgcn_s_barrier();
    __builtin_amdgcn_sched_barrier(0);
    COMPUTE(cur);
    __builtin_amdgcn_s_barrier();
    cur ^= 1;
  }

  const int gcb = col0 + (wn << 6) + (lc << 2);
#pragma unroll
  for (int mr = 0; mr < 8; ++mr) {
#pragma unroll
    for (int r = 0; r < 4; ++r) {
      const int gr = row0 + (wm << 7) + (mr << 4) + ((lane >> 4) << 2) + r;
      float t[4];
#pragma unroll
      for (int nr = 0; nr < 4; ++nr)
        t[nr] = acc[mr][nr][r] * ((gcb + nr) < acol ? alpha0 : alpha1);
      if constexpr (ROT) {
        if (col0 < 1024) {  // kk half only (block-uniform)
          const int j = gr & 127;
          const int cc = gcb & 63;
          float4 c4 = *reinterpret_cast<const float4*>(tab + j * 64 + cc);
          float4 s4 = *reinterpret_cast<const float4*>(tab + 8192 + j * 64 + cc);
          const float cs[4] = {c4.x, c4.y, c4.z, c4.w};
          const float sn[4] = {s4.x, s4.y, s4.z, s4.w};
          float o2[4];
#pragma unroll
          for (int nr = 0; nr < 4; ++nr) {
            const float pv = __shfl_xor(t[nr], 8);
            const float part = (cc < 32) ? -pv : pv;
            o2[nr] = t[nr] * cs[nr] + part * sn[nr];
          }
#pragma unroll
          for (int nr = 0; nr < 4; ++nr) t[nr] = o2[nr];
        }
      }
      if constexpr (HASBIAS) {
        float4 b4 = *reinterpret_cast<const float4*>(bias + gcb);
        t[0] += b4.x; t[1] += b4.y; t[2] += b4.z; t[3] += b4.w;
      }
      if constexpr (DOGELU) {
#pragma unroll
        for (int nr = 0; nr < 4; ++nr) {
          const float x = t[nr];
          t[nr] = 0.5f * x * (1.f + tanhf(0.7978845608f * (x + 0.044715f * x * x * x)));
        }
      }
      const size_t cb = (size_t)gr * ldc + coff + gcb;
      if constexpr (OT == 0) {
        *reinterpret_cast<float4*>((float*)C + cb) = make_float4(t[0], t[1], t[2], t[3]);
      } else {
        ushort4 o4 = {f2b(t[0]), f2b(t[1]), f2b(t[2]), f2b(t[3])};
        *reinterpret_cast<ushort4*>((u16*)C + cb) = o4;
      }
    }
  }
}

// ---------------------------------------------------------------------------
// 128x128 MFMA GEMM (verified): T1 row-major chunking, T2 both-sides swizzle,
// packed epilogue, ROT, DBUF, split-K.
// ---------------------------------------------------------------------------
template <int OT, bool HASBIAS, bool HASRES, bool DOGELU, bool ROT, int DBUF, int PART>
__global__ __launch_bounds__(256) void mgemm_k(
    const u16* __restrict__ A, const u16* __restrict__ Bt, void* __restrict__ C,
    int M, int K, int lda, int ldc, int coff, float alpha0, float alpha1, int acol,
    const float* __restrict__ bias, const float* __restrict__ res,
    const float* __restrict__ tab) {
  constexpr int NBUF = DBUF ? 2 : 1;
  __shared__ u16 As[NBUF][128 * 64];
  __shared__ u16 Bs[NBUF][128 * 64];
  const int tid = threadIdx.x;
  const int w = tid >> 6, lane = tid & 63;
  const int wr = w >> 1, wc = w & 1;
  const int koff = blockIdx.z * K;

  const int nwg = gridDim.x * gridDim.y;
  const int bid = blockIdx.y * gridDim.x + blockIdx.x;
  const int qq = nwg >> 3, r8 = nwg & 7;
  const int xcd = bid & 7, pos = bid >> 3;
  const int cbase = (xcd < r8) ? xcd * (qq + 1) : r8 * (qq + 1) + (xcd - r8) * qq;
  const int logical = cbase + pos;
  const int row0 = (logical / gridDim.x) << 7;
  const int col0 = (logical % gridDim.x) << 7;

  f32x4 acc[4][4] = {};

  auto STAGE = [&](int buf, int k0) {
#pragma unroll
    for (int i = 0; i < 4; ++i) {
      const int c = ((w << 2) + i) * 64 + lane;
      const int r = c >> 3;
      const int cbs = ((c & 7) ^ (r & 7)) << 3;
      const int r64 = r & 63;
      const int rB = (r & 64) | ((r64 & 15) << 2) | (r64 >> 4);
      gload16(A + (size_t)(row0 + r) * lda + koff + k0 + cbs, &As[buf][((w << 2) + i) << 9]);
      gload16(Bt + (size_t)(col0 + rB) * lda + koff + k0 + cbs, &Bs[buf][((w << 2) + i) << 9]);
    }
  };
  auto COMPUTE = [&](int buf) {
#pragma unroll
    for (int kk = 0; kk < 2; ++kk) {
      bfv8 af[4], bfr[4];
#pragma unroll
      for (int m = 0; m < 4; ++m) {
        const int ar = (wr << 6) + (m << 4) + (lane & 15);
        const int sl = ((kk << 2) | (lane >> 4)) ^ (ar & 7);
        af[m] = *reinterpret_cast<const bfv8*>(&As[buf][ar * 64 + (sl << 3)]);
      }
#pragma unroll
      for (int n = 0; n < 4; ++n) {
        const int br = (wc << 6) + (n << 4) + (lane & 15);
        const int sl = ((kk << 2) | (lane >> 4)) ^ (br & 7);
        bfr[n] = *reinterpret_cast<const bfv8*>(&Bs[buf][br * 64 + (sl << 3)]);
      }
#pragma unroll
      for (int m = 0; m < 4; ++m)
#pragma unroll
        for (int n = 0; n < 4; ++n)
          acc[m][n] = __builtin_amdgcn_mfma_f32_16x16x32_bf16(af[m], bfr[n], acc[m][n], 0, 0, 0);
    }
  };

  if constexpr (DBUF) {
    STAGE(0, 0);
    int cur = 0;
    for (int k0 = 0; k0 < K; k0 += 64) {
      if (k0 + 64 < K) {
        STAGE(cur ^ 1, k0 + 64);
        asm volatile("s_waitcnt vmcnt(8)" ::: "memory");
      } else {
        asm volatile("s_waitcnt vmcnt(0)" ::: "memory");
      }
      __builtin_amdgcn_s_barrier();
      __builtin_amdgcn_sched_barrier(0);
      COMPUTE(cur);
      __builtin_amdgcn_s_barrier();
      cur ^= 1;
    }
  } else {
    for (int k0 = 0; k0 < K; k0 += 64) {
      STAGE(0, k0);
      __syncthreads();
      COMPUTE(0);
      __syncthreads();
    }
  }

  const int lr = (lane >> 4) << 2;
  const int lc = lane & 15;
  const int gcb = col0 + (wc << 6) + (lc << 2);
#pragma unroll
  for (int m = 0; m < 4; ++m) {
#pragma unroll
    for (int r = 0; r < 4; ++r) {
      const int gr = row0 + (wr << 6) + (m << 4) + lr + r;
      float t[4];
#pragma unroll
      for (int n = 0; n < 4; ++n)
        t[n] = acc[m][n][r] * ((gcb + n) < acol ? alpha0 : alpha1);
      if constexpr (ROT) {
        const int j = gr & 127;
        const int cc = gcb & 63;
        float4 c4 = *reinterpret_cast<const float4*>(tab + j * 64 + cc);
        float4 s4 = *reinterpret_cast<const float4*>(tab + 8192 + j * 64 + cc);
        const float cs[4] = {c4.x, c4.y, c4.z, c4.w};
        const float sn[4] = {s4.x, s4.y, s4.z, s4.w};
        float o2[4];
#pragma unroll
        for (int n = 0; n < 4; ++n) {
          const float pv = __shfl_xor(t[n], 8);
          const float part = (cc < 32) ? -pv : pv;
          o2[n] = t[n] * cs[n] + part * sn[n];
        }
#pragma unroll
        for (int n = 0; n < 4; ++n) t[n] = o2[n];
      }
      if constexpr (HASBIAS) {
        float4 b4 = *reinterpret_cast<const float4*>(bias + gcb);
        t[0] += b4.x; t[1] += b4.y; t[2] += b4.z; t[3] += b4.w;
      }
      if constexpr (DOGELU) {
#pragma unroll
        for (int n = 0; n < 4; ++n) {
          const float x = t[n];
          t[n] = 0.5f * x * (1.f + tanhf(0.7978845608f * (x + 0.044715f * x * x * x)));
        }
      }
      size_t cb = (size_t)gr * ldc + coff + gcb;
      if constexpr (PART) cb += (size_t)blockIdx.z * M * ldc;
      if constexpr (HASRES) {
        float4 r4 = *reinterpret_cast<const float4*>(res + cb);
        t[0] += r4.x; t[1] += r4.y; t[2] += r4.z; t[3] += r4.w;
      }
      if constexpr (OT == 0) {
        float4 o4 = make_float4(t[0], t[1], t[2], t[3]);
        *reinterpret_cast<float4*>((float*)C + cb) = o4;
      } else {
        ushort4 o4 = {f2b(t[0]), f2b(t[1]), f2b(t[2]), f2b(t[3])};
        *reinterpret_cast<ushort4*>((u16*)C + cb) = o4;
      }
    }
  }
}

// split-K reduce: out = p0 + p1 + bias + res   (f32, 4096x1024)
__global__ __launch_bounds__(256) void reduce_k(const float* __restrict__ p,
                                                const float* __restrict__ bias,
                                                const float* __restrict__ res,
                                                float* __restrict__ out) {
  const int i = blockIdx.x * 256 + threadIdx.x;
  const int col = (i & 255) << 2;
  float4 a = reinterpret_cast<const float4*>(p)[i];
  float4 b = reinterpret_cast<const float4*>(p + (size_t)4096 * 1024)[i];
  float4 b4 = *reinterpret_cast<const float4*>(bias + col);
  float4 r4 = reinterpret_cast<const float4*>(res)[i];
  float4 o;
  o.x = a.x + b.x + b4.x + r4.x;
  o.y = a.y + b.y + b4.y + r4.y;
  o.z = a.z + b.z + b4.z + r4.z;
  o.w = a.w + b.w + b4.w + r4.w;
  reinterpret_cast<float4*>(out)[i] = o;
}

// cos/sin table for kk rotary
__global__ __launch_bounds__(256) void costab_k(const float* __restrict__ kpe,
                                                float* __restrict__ tab) {
  const int i = blockIdx.x * 256 + threadIdx.x;
  const float f = kpe[i];
  tab[i] = cosf(f);
  tab[8192 + i] = sinf(f);
}

// batched weight transpose: 8x (f32 [1024,1024] -> bf16 [1024,1024]^T)
struct WtArgs {
  const float* in[8];
  u16* out[8];
};
__global__ __launch_bounds__(256) void wtrans8_k(WtArgs a) {
  const float* in = a.in[blockIdx.z];
  u16* out = a.out[blockIdx.z];
  __shared__ float t[32][33];
  const int tx = threadIdx.x & 31, ty = threadIdx.x >> 5;
  const int r0 = blockIdx.y << 5, c0 = blockIdx.x << 5;
#pragma unroll
  for (int i = 0; i < 4; ++i)
    t[ty + 8 * i][tx] = in[(size_t)(r0 + ty + 8 * i) * 1024 + c0 + tx];
  __syncthreads();
#pragma unroll
  for (int i = 0; i < 4; ++i)
    out[(size_t)(c0 + ty + 8 * i) * 1024 + r0 + tx] = f2b(t[tx][ty + 8 * i]);
}

// generic weight transpose (W1/W2): f32 [K,N] -> bf16 [N,K]
__global__ __launch_bounds__(256) void wtrans_k(const float* __restrict__ in,
                                                u16* __restrict__ out, int K, int N) {
  __shared__ float t[32][33];
  const int tx = threadIdx.x & 31, ty = threadIdx.x >> 5;
  const int r0 = blockIdx.y << 5, c0 = blockIdx.x << 5;
#pragma unroll
  for (int i = 0; i < 4; ++i)
    t[ty + 8 * i][tx] = in[(size_t)(r0 + ty + 8 * i) * N + c0 + tx];
  __syncthreads();
#pragma unroll
  for (int i = 0; i < 4; ++i)
    out[(size_t)(c0 + ty + 8 * i) * K + r0 + tx] = f2b(t[tx][ty + 8 * i]);
}

// flat f32 -> bf16 cast
__global__ __launch_bounds__(256) void cast_k(const float* __restrict__ in,
                                              u16* __restrict__ out) {
  const int i = blockIdx.x * 256 + threadIdx.x;
  float4 v = reinterpret_cast<const float4*>(in)[i];
  ushort4 o = {f2b(v.x), f2b(v.y), f2b(v.z), f2b(v.w)};
  reinterpret_cast<ushort4*>(out)[i] = o;
}

// LayerNorm rows of 1024; f32 in, bf16 out (ln1)
__global__ __launch_bounds__(256) void ln_k(const float* __restrict__ in,
                                            const float* __restrict__ g,
                                            const float* __restrict__ b,
                                            u16* __restrict__ out) {
  const int tid = threadIdx.x;
  const int c = tid << 2;
  const size_t base = (size_t)blockIdx.x * DM;
  float4 x = *reinterpret_cast<const float4*>(in + base + c);
  float s = x.x + x.y + x.z + x.w;
  float ss = x.x * x.x + x.y * x.y + x.z * x.z + x.w * x.w;
#pragma unroll
  for (int m = 1; m < 64; m <<= 1) {
    s += __shfl_xor(s, m, 64);
    ss += __shfl_xor(ss, m, 64);
  }
  __shared__ float ls[4], lss[4];
  if ((tid & 63) == 0) { ls[tid >> 6] = s; lss[tid >> 6] = ss; }
  __syncthreads();
  s = (ls[0] + ls[1]) + (ls[2] + ls[3]);
  ss = (lss[0] + lss[1]) + (lss[2] + lss[3]);
  const float mu = s * (1.f / DM);
  const float var = ss * (1.f / DM) - mu * mu;
  const float rstd = rsqrtf(var + 1e-5f);
  float4 g4 = *reinterpret_cast<const float4*>(g + c);
  float4 b4 = *reinterpret_cast<const float4*>(b + c);
  ushort4 u;
  u.x = f2b((x.x - mu) * rstd * g4.x + b4.x);
  u.y = f2b((x.y - mu) * rstd * g4.y + b4.y);
  u.z = f2b((x.z - mu) * rstd * g4.z + b4.z);
  u.w = f2b((x.w - mu) * rstd * g4.w + b4.w);
  *reinterpret_cast<ushort4*>(out + base + c) = u;
}

// LN2 with fused xq-shift
__global__ __launch_bounds__(256) void ln2x_k(const float* __restrict__ in,
                                              const float* __restrict__ g,
                                              const float* __restrict__ b,
                                              float* __restrict__ hs,
                                              u16* __restrict__ xq) {
  const int tid = threadIdx.x;
  const int c = tid << 2;
  const int row = blockIdx.x;
  const size_t base = (size_t)row * DM;
  float4 x = *reinterpret_cast<const float4*>(in + base + c);
  float s = x.x + x.y + x.z + x.w;
  float ss = x.x * x.x + x.y * x.y + x.z * x.z + x.w * x.w;
#pragma unroll
  for (int m = 1; m < 64; m <<= 1) {
    s += __shfl_xor(s, m, 64);
    ss += __shfl_xor(ss, m, 64);
  }
  __shared__ float ls[4], lss[4];
  if ((tid & 63) == 0) { ls[tid >> 6] = s; lss[tid >> 6] = ss; }
  __syncthreads();
  s = (ls[0] + ls[1]) + (ls[2] + ls[3]);
  ss = (lss[0] + lss[1]) + (lss[2] + lss[3]);
  const float mu = s * (1.f / DM);
  const float var = ss * (1.f / DM) - mu * mu;
  const float rstd = rsqrtf(var + 1e-5f);
  float4 g4 = *reinterpret_cast<const float4*>(g + c);
  float4 b4 = *reinterpret_cast<const float4*>(b + c);
  float4 o;
  o.x = (x.x - mu) * rstd * g4.x + b4.x;
  o.y = (x.y - mu) * rstd * g4.y + b4.y;
  o.z = (x.z - mu) * rstd * g4.z + b4.z;
  o.w = (x.w - mu) * rstd * g4.w + b4.w;
  *reinterpret_cast<float4*>(hs + base + c) = o;
  const int local = row & (SEQ - 1);
  const int bb = row >> 10;
  if (local >= 63) {
    ushort4 u = {f2b(o.x), f2b(o.y), f2b(o.z), f2b(o.w)};
    *reinterpret_cast<ushort4*>(xq + (size_t)((bb << 10) + local - 63) * DM + c) = u;
  } else {
    ushort4 z = {0, 0, 0, 0};
    *reinterpret_cast<ushort4*>(xq + (size_t)((bb << 10) + 961 + local) * DM + c) = z;
  }
}

// t5norm(shift_right_63(cca_bf16) + hs_f32) * w -> bf16
__global__ __launch_bounds__(256) void t5_k(const u16* __restrict__ cca,
                                            const float* __restrict__ hs,
                                            const float* __restrict__ w,
                                            u16* __restrict__ out) {
  const int tid = threadIdx.x;
  const int row = blockIdx.x;
  const int t = row & (SEQ - 1);
  const int c = tid << 2;
  const size_t base = (size_t)row * DM;
  float4 x = *reinterpret_cast<const float4*>(hs + base + c);
  if (t >= 63) {
    ushort4 cu = *reinterpret_cast<const ushort4*>(cca + base - (size_t)63 * DM + c);
    x.x += u2f(cu.x); x.y += u2f(cu.y); x.z += u2f(cu.z); x.w += u2f(cu.w);
  }
  float ss = x.x * x.x + x.y * x.y + x.z * x.z + x.w * x.w;
#pragma unroll
  for (int m = 1; m < 64; m <<= 1) ss += __shfl_xor(ss, m, 64);
  __shared__ float lss[4];
  if ((tid & 63) == 0) lss[tid >> 6] = ss;
  __syncthreads();
  ss = (lss[0] + lss[1]) + (lss[2] + lss[3]);
  const float rms = sqrtf(ss * (1.f / DM));
  const float inv = 1.f / fmaxf(rms, 1e-6f);
  float4 w4 = *reinterpret_cast<const float4*>(w + c);
  ushort4 o = {f2b(x.x * inv * w4.x), f2b(x.y * inv * w4.y),
               f2b(x.z * inv * w4.z), f2b(x.w * inv * w4.w)};
  *reinterpret_cast<ushort4*>(out + base + c) = o;
}

// rotary on q_c: row 0 of each 64-row chunk, freqs qpe[63]
__global__ __launch_bounds__(256) void rotq_k(u16* __restrict__ q,
                                              const float* __restrict__ qpe) {
  __shared__ float rb[DM];
  const size_t base = (size_t)blockIdx.x * 64 * DM;
  const int e = threadIdx.x << 2;
  ushort4 u = *reinterpret_cast<const ushort4*>(q + base + e);
  rb[e + 0] = u2f(u.x); rb[e + 1] = u2f(u.y); rb[e + 2] = u2f(u.z); rb[e + 3] = u2f(u.w);
  __syncthreads();
  u16 ov[4];
#pragma unroll
  for (int k = 0; k < 4; ++k) {
    const int ee = e + k;
    const int cc = ee & 63;
    const float f = qpe[63 * 64 + cc];
    const float t1 = rb[ee];
    const float part = (cc < 32) ? -rb[ee + 32] : rb[ee - 32];
    ov[k] = f2b(t1 * cosf(f) + part * sinf(f));
  }
  ushort4 o = {ov[0], ov[1], ov[2], ov[3]};
  *reinterpret_cast<ushort4*>(q + base + e) = o;
}

// vt slot swizzle: physical slot = logical slot ^ ((d>>2)&7)
__device__ __forceinline__ int vswz(int d, int k) {
  return (k & 7) | (((k >> 3) ^ ((d >> 2) & 7)) << 3);
}

// ---------------------------------------------------------------------------
// MFMA causal self-attention, QB=128, 8 waves, pitch 88, balanced qt map.
// ---------------------------------------------------------------------------
__global__ __launch_bounds__(512) void attn_self_k(const u16* __restrict__ qkv,
                                                   u16* __restrict__ o) {
  const int h = blockIdx.y, b = blockIdx.z;
  const int qt = (blockIdx.z < 2) ? blockIdx.x : (7 - blockIdx.x);
  __shared__ u16 qs[128][88];
  __shared__ u16 ks[64][88];
  __shared__ u16 vt[64][88];
  __shared__ u16 ps[128][88];
  const int tid = threadIdx.x;
  const int w = tid >> 6, lane = tid & 63;
  const int strip = w << 4;
  const int sloc = (w & 3) << 4;
  const int lrow = lane & 15, lk = lane >> 4;
  const int rowb = b * SEQ;
  const int hoff = h * DHD;
  const int qrow0 = qt << 7;

#pragma unroll
  for (int rp = 0; rp < 4; ++rp) {
    const int fi = tid + (rp << 9);
    const int r = fi >> 4, c4 = (fi & 15) << 2;
    *reinterpret_cast<ushort4*>(&qs[r][c4]) =
        *reinterpret_cast<const ushort4*>(qkv + (size_t)(rowb + qrow0 + r) * 3072 + hoff + c4);
  }

  ushort4 kr[2], vr[2];
  auto loadKV = [&](int kt) {
#pragma unroll
    for (int rp = 0; rp < 2; ++rp) {
      const int fi = tid + (rp << 9);
      const int r = fi >> 4, c4 = (fi & 15) << 2;
      const size_t g = (size_t)(rowb + kt * 64 + r) * 3072 + hoff + c4;
      kr[rp] = *reinterpret_cast<const ushort4*>(qkv + g + 1024);
      vr[rp] = *reinterpret_cast<const ushort4*>(qkv + g + 2048);
    }
  };
  loadKV(0);

  const int ktmax = 2 * qt + 1;
  const int ktd = 2 * qt + (w >> 2);

  float mrun[4], lrun[4];
  f32x4 accO[4] = {};
#pragma unroll
  for (int r = 0; r < 4; ++r) { mrun[r] = -1e30f; lrun[r] = 0.f; }

  for (int kt = 0; kt <= ktmax; ++kt) {
    __syncthreads();
#pragma unroll
    for (int rp = 0; rp < 2; ++rp) {
      const int fi = tid + (rp << 9);
      const int r = fi >> 4, c4 = (fi & 15) << 2;
      *reinterpret_cast<ushort4*>(&ks[r][c4]) = kr[rp];
      vt[c4 + 0][vswz(c4 + 0, r)] = vr[rp].x;
      vt[c4 + 1][vswz(c4 + 1, r)] = vr[rp].y;
      vt[c4 + 2][vswz(c4 + 2, r)] = vr[rp].z;
      vt[c4 + 3][vswz(c4 + 3, r)] = vr[rp].w;
    }
    __syncthreads();
    if (kt < ktmax) loadKV(kt + 1);

    if (kt <= ktd) {
      f32x4 sacc[4] = {};
#pragma unroll
      for (int kk = 0; kk < 2; ++kk) {
        bfv8 qf = *reinterpret_cast<const bfv8*>(&qs[strip + lrow][(kk << 5) + (lk << 3)]);
#pragma unroll
        for (int n = 0; n < 4; ++n) {
          bfv8 kf = *reinterpret_cast<const bfv8*>(&ks[(n << 4) + lrow][(kk << 5) + (lk << 3)]);
          sacc[n] = __builtin_amdgcn_mfma_f32_16x16x32_bf16(qf, kf, sacc[n], 0, 0, 0);
        }
      }
      if (kt == ktd) {
#pragma unroll
        for (int n = 0; n < 4; ++n)
#pragma unroll
          for (int r = 0; r < 4; ++r)
            if ((n << 4) + lrow > sloc + (lk << 2) + r) sacc[n][r] = -1e30f;
      }
#pragma unroll
      for (int r = 0; r < 4; ++r) {
        float mt = fmaxf(fmaxf(sacc[0][r], sacc[1][r]), fmaxf(sacc[2][r], sacc[3][r]));
        mt = fmaxf(mt, __shfl_xor(mt, 1));
        mt = fmaxf(mt, __shfl_xor(mt, 2));
        mt = fmaxf(mt, __shfl_xor(mt, 4));
        mt = fmaxf(mt, __shfl_xor(mt, 8));
        const float nm = fmaxf(mrun[r], mt);
        const float f = __expf(mrun[r] - nm);
        mrun[r] = nm;
        float p0 = __expf(sacc[0][r] - nm);
        float p1 = __expf(sacc[1][r] - nm);
        float p2 = __expf(sacc[2][r] - nm);
        float p3 = __expf(sacc[3][r] - nm);
        float rs = (p0 + p1) + (p2 + p3);
        rs += __shfl_xor(rs, 1);
        rs += __shfl_xor(rs, 2);
        rs += __shfl_xor(rs, 4);
        rs += __shfl_xor(rs, 8);
        lrun[r] = lrun[r] * f + rs;
#pragma unroll
        for (int nd = 0; nd < 4; ++nd) accO[nd][r] *= f;
        const int prow = strip + (lk << 2) + r;
        ps[prow][lrow +  0] = f2b(p0);
        ps[prow][lrow + 16] = f2b(p1);
        ps[prow][lrow + 32] = f2b(p2);
        ps[prow][lrow + 48] = f2b(p3);
      }
#pragma unroll
      for (int kk = 0; kk < 2; ++kk) {
        bfv8 pf = *reinterpret_cast<const bfv8*>(&ps[strip + lrow][(kk << 5) + (lk << 3)]);
#pragma unroll
        for (int nd = 0; nd < 4; ++nd) {
          const int vd = (nd << 4) + lrow;
          const int slot = ((kk << 2) | lk) ^ ((vd >> 2) & 7);
          bfv8 vf = *reinterpret_cast<const bfv8*>(&vt[vd][slot << 3]);
          accO[nd] = __builtin_amdgcn_mfma_f32_16x16x32_bf16(pf, vf, accO[nd], 0, 0, 0);
        }
      }
    }
  }
#pragma unroll
  for (int r = 0; r < 4; ++r) {
    const float inv = 1.f / lrun[r];
    const size_t rowoff = (size_t)(rowb + qrow0 + strip + (lk << 2) + r) * DM + hoff;
#pragma unroll
    for (int nd = 0; nd < 4; ++nd)
      o[rowoff + (nd << 4) + lrow] = f2b(accO[nd][r] * inv);
  }
}

// ---------------------------------------------------------------------------
// MFMA chunked cross-attention: 257 keys, kk/vv fused [16384][2048]. Pitch 88.
// ---------------------------------------------------------------------------
__global__ __launch_bounds__(256) void attn_cca_k(
    const u16* __restrict__ q, const u16* __restrict__ kv,
    const float* __restrict__ nullk, const float* __restrict__ nullv,
    u16* __restrict__ o) {
  const int h = blockIdx.y, bk = blockIdx.z;
  __shared__ u16 qs[64][88];
  __shared__ u16 ks[64][88];
  __shared__ u16 vt[64][88];
  __shared__ u16 ps[64][88];
  const int tid = threadIdx.x;
  const int w = tid >> 6, lane = tid & 63;
  const int strip = w << 4;
  const int lrow = lane & 15, lk = lane >> 4;
  const int hoff = h * DHD;
  const size_t qbase = (size_t)bk * 64 * DM + hoff;

#pragma unroll
  for (int rp = 0; rp < 4; ++rp) {
    const int fi = tid + (rp << 8);
    const int r = fi >> 4, c4 = (fi & 15) << 2;
    *reinterpret_cast<ushort4*>(&qs[r][c4]) =
        *reinterpret_cast<const ushort4*>(q + qbase + (size_t)r * DM + c4);
  }

  ushort4 kr[4], vr[4];
  auto loadKV = [&](int kt) {
#pragma unroll
    for (int rp = 0; rp < 4; ++rp) {
      const int fi = tid + (rp << 8);
      const int r = fi >> 4, c4 = (fi & 15) << 2;
      const int kj = kt * 64 + r;
      ushort4 ku = {0, 0, 0, 0}, vu = {0, 0, 0, 0};
      if (kj == 0) {
        float4 nk4 = *reinterpret_cast<const float4*>(nullk + hoff + c4);
        float4 nv4 = *reinterpret_cast<const float4*>(nullv + hoff + c4);
        ku = {f2b(nk4.x), f2b(nk4.y), f2b(nk4.z), f2b(nk4.w)};
        vu = {f2b(nv4.x), f2b(nv4.y), f2b(nv4.z), f2b(nv4.w)};
      } else if (kj <= 256) {
        const size_t g = (size_t)(bk * 256 + kj - 1) * 2048 + hoff + c4;
        ku = *reinterpret_cast<const ushort4*>(kv + g);
        vu = *reinterpret_cast<const ushort4*>(kv + g + 1024);
      }
      kr[rp] = ku; vr[rp] = vu;
    }
  };
  loadKV(0);

  float mrun[4], lrun[4];
  f32x4 accO[4] = {};
#pragma unroll
  for (int r = 0; r < 4; ++r) { mrun[r] = -1e30f; lrun[r] = 0.f; }

  for (int kt = 0; kt < 5; ++kt) {
    __syncthreads();
#pragma unroll
    for (int rp = 0; rp < 4; ++rp) {
      const int fi = tid + (rp << 8);
      const int r = fi >> 4, c4 = (fi & 15) << 2;
      *reinterpret_cast<ushort4*>(&ks[r][c4]) = kr[rp];
      vt[c4 + 0][vswz(c4 + 0, r)] = vr[rp].x;
      vt[c4 + 1][vswz(c4 + 1, r)] = vr[rp].y;
      vt[c4 + 2][vswz(c4 + 2, r)] = vr[rp].z;
      vt[c4 + 3][vswz(c4 + 3, r)] = vr[rp].w;
    }
    __syncthreads();
    if (kt < 4) loadKV(kt + 1);

    f32x4 sacc[4] = {};
#pragma unroll
    for (int kk = 0; kk < 2; ++kk) {
      bfv8 qf = *reinterpret_cast<const bfv8*>(&qs[strip + lrow][(kk << 5) + (lk << 3)]);
#pragma unroll
      for (int n = 0; n < 4; ++n) {
        bfv8 kf = *reinterpret_cast<const bfv8*>(&ks[(n << 4) + lrow][(kk << 5) + (lk << 3)]);
        sacc[n] = __builtin_amdgcn_mfma_f32_16x16x32_bf16(qf, kf, sacc[n], 0, 0, 0);
      }
    }
    if (kt == 4) {
#pragma unroll
      for (int n = 0; n < 4; ++n)
#pragma unroll
        for (int r = 0; r < 4; ++r)
          if ((n << 4) + lrow >= 1) sacc[n][r] = -1e30f;
    }
#pragma unroll
    for (int r = 0; r < 4; ++r) {
      float mt = fmaxf(fmaxf(sacc[0][r], sacc[1][r]), fmaxf(sacc[2][r], sacc[3][r]));
      mt = fmaxf(mt, __shfl_xor(mt, 1));
      mt = fmaxf(mt, __shfl_xor(mt, 2));
      mt = fmaxf(mt, __shfl_xor(mt, 4));
      mt = fmaxf(mt, __shfl_xor(mt, 8));
      const float nm = fmaxf(mrun[r], mt);
      const float f = __expf(mrun[r] - nm);
      mrun[r] = nm;
      float p0 = __expf(sacc[0][r] - nm);
      float p1 = __expf(sacc[1][r] - nm);
      float p2 = __expf(sacc[2][r] - nm);
      float p3 = __expf(sacc[3][r] - nm);
      float rs = (p0 + p1) + (p2 + p3);
      rs += __shfl_xor(rs, 1);
      rs += __shfl_xor(rs, 2);
      rs += __shfl_xor(rs, 4);
      rs += __shfl_xor(rs, 8);
      lrun[r] = lrun[r] * f + rs;
#pragma unroll
      for (int nd = 0; nd < 4; ++nd) accO[nd][r] *= f;
      const int prow = strip + (lk << 2) + r;
      ps[prow][lrow +  0] = f2b(p0);
      ps[prow][lrow + 16] = f2b(p1);
      ps[prow][lrow + 32] = f2b(p2);
      ps[prow][lrow + 48] = f2b(p3);
    }
#pragma unroll
    for (int kk = 0; kk < 2; ++kk) {
      bfv8 pf = *reinterpret_cast<const bfv8*>(&ps[strip + lrow][(kk << 5) + (lk << 3)]);
#pragma unroll
      for (int nd = 0; nd < 4; ++nd) {
        const int vd = (nd << 4) + lrow;
        const int slot = ((kk << 2) | lk) ^ ((vd >> 2) & 7);
        bfv8 vf = *reinterpret_cast<const bfv8*>(&vt[vd][slot << 3]);
        accO[nd] = __builtin_amdgcn_mfma_f32_16x16x32_bf16(pf, vf, accO[nd], 0, 0, 0);
      }
    }
  }
#pragma unroll
  for (int r = 0; r < 4; ++r) {
    const float inv = 1.f / lrun[r];
    const size_t rowoff = (size_t)(bk * 64 + strip + (lk << 2) + r) * DM + hoff;
#pragma unroll
    for (int nd = 0; nd < 4; ++nd)
      o[rowoff + (nd << 4) + lrow] = f2b(accO[nd][r] * inv);
  }
}

// ---------------------------------------------------------------------------
extern "C" void kernel_launch(void* const* d_in, const int* in_sizes, int n_in,
                              void* d_out, int out_size, void* d_ws, size_t ws_size,
                              hipStream_t stream) {
  const float* hidden    = (const float*)d_in[0];
  const float* retrieval = (const float*)d_in[1];
  const float* q_pos     = (const float*)d_in[2];
  const float* k_pos     = (const float*)d_in[3];
  const float* ln1_g     = (const float*)d_in[4];
  const float* ln1_b     = (const float*)d_in[5];
  const float* Wq_s      = (const float*)d_in[6];
  const float* Wk_s      = (const float*)d_in[7];
  const float* Wv_s      = (const float*)d_in[8];
  const float* Wo_s      = (const float*)d_in[9];
  const float* bo_s      = (const float*)d_in[10];
  const float* ln2_g     = (const float*)d_in[11];
  const float* ln2_b     = (const float*)d_in[12];
  const float* Wq_c      = (const float*)d_in[13];
  const float* Wk_c      = (const float*)d_in[14];
  const float* Wv_c      = (const float*)d_in[15];
  const float* Wo_c      = (const float*)d_in[16];
  const float* bo_c      = (const float*)d_in[17];
  const float* null_k    = (const float*)d_in[18];
  const float* null_v    = (const float*)d_in[19];
  const float* post_w    = (const float*)d_in[20];
  const float* W1        = (const float*)d_in[21];
  const float* b1        = (const float*)d_in[22];
  const float* W2        = (const float*)d_in[23];
  const float* b2        = (const float*)d_in[24];
  float* out = (float*)d_out;

  constexpr size_t MB = 1024 * 1024;
  constexpr size_t ME = 1024 * 1024;
  char* W = (char*)d_ws;
  u16* Wt_qkv  = (u16*)(W + 0 * MB);    // [3072][1024] 6MB
  u16* Wt_os   = (u16*)(W + 6 * MB);    // 2MB
  u16* Wt_qc   = (u16*)(W + 8 * MB);    // 2MB
  u16* Wt_kcvc = (u16*)(W + 10 * MB);   // [2048][1024] 4MB
  u16* Wt_oc   = (u16*)(W + 14 * MB);   // 2MB
  u16* W1t     = (u16*)(W + 16 * MB);   // [4096][1024] 8MB
  u16* W2t     = (u16*)(W + 24 * MB);   // [1024][4096] 8MB
  float* s5    = (float*)(W + 32 * MB); // hs f32, 16MB [persist]
  float* s0    = (float*)(W + 48 * MB); // f32 16MB    [5-6]
  u16* retb    = (u16*)(W + 48 * MB);   // 32MB        [7-9]
  u16* ccab    = (u16*)(W + 48 * MB);   // 8MB         [10-11]
  u16* ccapb   = (u16*)(W + 56 * MB);   // 8MB         [11-12]
  u16* xb      = (u16*)(W + 64 * MB);   // 8MB         [2-3]
  u16* t5b     = (u16*)(W + 64 * MB);   // 8MB         [12-13]
  u16* attnb   = (u16*)(W + 80 * MB);   // 8MB         [4-5]
  u16* xqb     = (u16*)(W + 80 * MB);   // 8MB         [6-8]
  float* tab   = (float*)(W + 80 * MB); // 64KB        [8.5-9]
  u16* qkvb    = (u16*)(W + 88 * MB);   // 24MB        [3-4]
  u16* qcb     = (u16*)(W + 88 * MB);   // 8MB         [8-10]
  u16* kkvvb   = (u16*)(W + 96 * MB);   // 64MB        [9-10]
  u16* ff1b    = (u16*)(W + 96 * MB);   // 32MB        [13-14]
  float* fpart = (float*)(W + 128 * MB);// 2x16MB f32  [14]

  const dim3 blk(256);

  WtArgs wa;
  wa.in[0] = Wq_s; wa.out[0] = Wt_qkv + 0 * ME;
  wa.in[1] = Wk_s; wa.out[1] = Wt_qkv + 1 * ME;
  wa.in[2] = Wv_s; wa.out[2] = Wt_qkv + 2 * ME;
  wa.in[3] = Wo_s; wa.out[3] = Wt_os;
  wa.in[4] = Wq_c; wa.out[4] = Wt_qc;
  wa.in[5] = Wk_c; wa.out[5] = Wt_kcvc + 0 * ME;
  wa.in[6] = Wv_c; wa.out[6] = Wt_kcvc + 1 * ME;
  wa.in[7] = Wo_c; wa.out[7] = Wt_oc;
  wtrans8_k<<<dim3(32, 32, 8), blk, 0, stream>>>(wa);
  wtrans_k<<<dim3(128, 32), blk, 0, stream>>>(W1, W1t, 1024, 4096);
  wtrans_k<<<dim3(32, 128), blk, 0, stream>>>(W2, W2t, 4096, 1024);

  // 2. ln1 -> xb
  ln_k<<<dim3(4096), blk, 0, stream>>>(hidden, ln1_g, ln1_b, xb);
  // 3. fused qkv projection (256^2 tile)
  mgemm256_k<1, false, false, false><<<dim3(12, 16), dim3(512), 0, stream>>>(
      xb, Wt_qkv, qkvb, 4096, 1024, 1024, 3072, 0, 0.125f, 1.f, 1024, nullptr, nullptr);
  // 4. causal self-attention (QB=128, 8 waves, balanced qt map)
  attn_self_k<<<dim3(8, 16, 4), dim3(512), 0, stream>>>(qkvb, attnb);
  // 5. o-proj + residual (DBUF 128^2)
  mgemm_k<0, true, true, false, false, 1, 0><<<dim3(8, 32), blk, 0, stream>>>(
      attnb, Wt_os, s0, 4096, 1024, 1024, 1024, 0, 1.f, 1.f, 0, bo_s, hidden, nullptr);
  // 6. ln2 -> s5 + xqb
  ln2x_k<<<dim3(4096), blk, 0, stream>>>(s0, ln2_g, ln2_b, s5, xqb);
  // 7. cast retrieval
  cast_k<<<dim3(16384), blk, 0, stream>>>(retrieval, retb);
  // 8. q_c projection (DBUF 128^2)
  mgemm_k<1, false, false, false, false, 1, 0><<<dim3(8, 32), blk, 0, stream>>>(
      xqb, Wt_qc, qcb, 4096, 1024, 1024, 1024, 0, 1.f, 0.125f, 0, nullptr, nullptr, nullptr);
  rotq_k<<<dim3(64), blk, 0, stream>>>(qcb, q_pos);
  // 8.5 cos/sin table
  costab_k<<<dim3(32), blk, 0, stream>>>(k_pos, tab);
  // 9. fused kk|vv projection, one N=2048 launch; rotary on kk half only
  mgemm256_k<1, false, false, true><<<dim3(8, 64), dim3(512), 0, stream>>>(
      retb, Wt_kcvc, kkvvb, 16384, 1024, 1024, 2048, 0, 1.f, 1.f, 0, nullptr, tab);
  // 10. cross attention
  attn_cca_k<<<dim3(1, 16, 64), blk, 0, stream>>>(qcb, kkvvb, null_k, null_v, ccab);
  // 11. cca projection (DBUF 128^2)
  mgemm_k<1, true, false, false, false, 1, 0><<<dim3(8, 32), blk, 0, stream>>>(
      ccab, Wt_oc, ccapb, 4096, 1024, 1024, 1024, 0, 1.f, 1.f, 0, bo_c, nullptr, nullptr);
  // 12. t5norm
  t5_k<<<dim3(4096), blk, 0, stream>>>(ccapb, s5, post_w, t5b);
  // 13. FFN1 (256^2 tile, gelu)
  mgemm256_k<1, true, true, false><<<dim3(16, 16), dim3(512), 0, stream>>>(
      t5b, W1t, ff1b, 4096, 1024, 1024, 4096, 0, 1.f, 1.f, 0, b1, nullptr);
  // 14. FFN2 split-K=2 -> f32 partials (DBUF 128^2)
  mgemm_k<0, false, false, false, false, 1, 1><<<dim3(8, 32, 2), blk, 0, stream>>>(
      ff1b, W2t, fpart, 4096, 2048, 4096, 1024, 0, 1.f, 1.f, 0, nullptr, nullptr, nullptr);
  // 14b. reduce partials + bias + residual -> out
  reduce_k<<<dim3(4096), blk, 0, stream>>>(fpart, b2, s5, out);
}